// Round 10
// baseline (27.325 us; speedup 1.0000x reference)
//
#include <hip/hip_runtime.h>
#include <hip/hip_bf16.h>

#define DX 128
#define DH 128
#define HID 512
#define NB 4096
#define ROWS 16
#define OUTC 129   // 128 v cols + 1 div col

typedef __attribute__((ext_vector_type(4))) float f32x4;
typedef __attribute__((ext_vector_type(4))) float float4v;
typedef __attribute__((ext_vector_type(8))) short bf16x8;
typedef __attribute__((ext_vector_type(4))) short bf16x4;

// RNE float -> bf16 (bit pattern in a short)
__device__ inline short f2bf(float f) {
    unsigned u = __float_as_uint(f);
    unsigned r = (u + 0x7fffu + ((u >> 16) & 1u)) >> 16;
    return (short)r;
}

__device__ inline float fast_tanh(float x) {
    float e = __expf(2.0f * x);
    float r = __builtin_amdgcn_rcpf(e + 1.0f);
    return 1.0f - 2.0f * r;
}

// -------- prep v2 (unchanged, proven): wave-per-tile coalesced repack --------
// W1P layout: [nt(32)][ks(8)][lane(64)][e(8)] -> W1[(ks*32+(l>>4)*8+e), nt*16+(l&15)]
// W2P layout: [nt(8)][ks(16)][lane(64)][e(8)] -> W2[(ks*32+(l>>4)*8+e), nt*16+(l&15)]
__global__ __launch_bounds__(256) void prep_kernel(
    const float* __restrict__ W1, const float* __restrict__ W2,
    float* __restrict__ c, short* __restrict__ w1p, short* __restrict__ w2p)
{
    __shared__ float tile[4][32][17];

    const int tid  = threadIdx.x;
    const int lane = tid & 63;
    const int w    = tid >> 6;
    const int l15  = lane & 15;
    const int l4   = lane >> 4;
    const int W    = blockIdx.x * 4 + w;

    if (W < 256) {                         // w1p tile
        int nt = W >> 3, ks = W & 7;
        int m0 = ks * 32, n0 = nt * 16;
        #pragma unroll
        for (int p = 0; p < 8; ++p) {
            int r = p * 4 + l4;
            tile[w][r][l15] = W1[(m0 + r) * HID + n0 + l15];
        }
    } else if (W < 384) {                  // w2p tile
        int idx = W - 256;
        int nt = idx >> 4, ks = idx & 15;
        int k0 = ks * 32, n0 = nt * 16;
        #pragma unroll
        for (int p = 0; p < 8; ++p) {
            int r = p * 4 + l4;
            tile[w][r][l15] = W2[(k0 + r) * DX + n0 + l15];
        }
    }
    __syncthreads();

    if (W < 256) {
        bf16x8 v;
        #pragma unroll
        for (int e = 0; e < 8; ++e) v[e] = f2bf(tile[w][l4 * 8 + e][l15]);
        *(bf16x8*)&w1p[W * 512 + lane * 8] = v;
    } else if (W < 384) {
        int idx = W - 256;
        bf16x8 v;
        #pragma unroll
        for (int e = 0; e < 8; ++e) v[e] = f2bf(tile[w][l4 * 8 + e][l15]);
        *(bf16x8*)&w2p[idx * 512 + lane * 8] = v;
    } else if (W < 896) {                  // c[k] = sum_i W1[i,k]*W2[k,i]
        int k = W - 384;
        float p = W1[lane * HID + k] * W2[k * DX + lane]
                + W1[(lane + 64) * HID + k] * W2[k * DX + lane + 64];
        for (int m = 1; m < 64; m <<= 1) p += __shfl_xor(p, m, 64);
        if (lane == 0) c[k] = p;
    }
}

// -------- cvf v5: NO input staging, NO barrier 1 --------
// GEMM1 (swapped): wave w (0..15) owns hidden cols [w*32, w*32+32); acc = pre^T.
//   z B-frags loaded DIRECTLY from global: lane l -> z[row0 + l15][ks*32 + l4*8 + e]
//   (h/hn: 32B-aligned float4 x2; x: scalar loads, state stride 129 is 4B-aligned).
//   The 25 KB input block is L1-resident; 16-wave redundancy is L1-served.
// epilogue A: tanh -> ab (b64 writes); div partial = local sum + 2 shfl.
// GEMM2: waves 0..7 full-K=512 from ab LDS + w2p; wave 8 finalizes div.
// Single __syncthreads() in the whole kernel (ab/divp producer->consumer).
__global__ __launch_bounds__(1024) void cvf_kernel(
    const float* __restrict__ state, const float* __restrict__ h_,
    const float* __restrict__ hn_, const float* __restrict__ tptr,
    const float* __restrict__ gsptr, const float* __restrict__ W1,
    const float* __restrict__ b1, const float* __restrict__ b2,
    const float* __restrict__ c, const short* __restrict__ w1p,
    const short* __restrict__ w2p, float* __restrict__ out)
{
    __shared__ short ab_h[ROWS][HID + 8];    // 1040 B rows: b128-aligned
    __shared__ short ab_n[ROWS][HID + 8];
    __shared__ float divp[2][16][ROWS];

    const int tid  = threadIdx.x;
    const int lane = tid & 63;
    const int w    = tid >> 6;         // wave 0..15
    const int l15  = lane & 15;
    const int l4   = lane >> 4;
    const int row0 = blockIdx.x * ROWS;
    const float t  = tptr[0];
    const float gs = gsptr[0];

    // ---- W1 frags + base fold (b1 + t*W1[256,:]) ----
    bf16x8 bx[2][4], bh[2][4];
    f32x4 base[2];
    #pragma unroll
    for (int j = 0; j < 2; ++j) {
        #pragma unroll
        for (int ks = 0; ks < 4; ++ks) {
            bx[j][ks] = *(const bf16x8*)&w1p[(((w * 2 + j) * 8 + ks) * 64 + lane) * 8];
            bh[j][ks] = *(const bf16x8*)&w1p[(((w * 2 + j) * 8 + 4 + ks) * 64 + lane) * 8];
        }
        int k0 = w * 32 + j * 16 + l4 * 4;          // 4 consecutive k per lane
        float4v bb = *(const float4v*)&b1[k0];
        float4v tw = *(const float4v*)&W1[256 * HID + k0];
        #pragma unroll
        for (int q = 0; q < 4; ++q) base[j][q] = bb[q] + t * tw[q];
    }

    // ---- z B-frags direct from global (no LDS, no barrier) ----
    bf16x8 ax[4], ah[4], an[4];
    {
        const float* xrow = state + (row0 + l15) * OUTC;   // 4B-aligned only
        const float* hrow = h_    + (row0 + l15) * DH;     // 32B-aligned at our offsets
        const float* nrow = hn_   + (row0 + l15) * DH;
        #pragma unroll
        for (int ks = 0; ks < 4; ++ks) {
            int off = ks * 32 + l4 * 8;
            bf16x8 vx;
            #pragma unroll
            for (int e = 0; e < 8; ++e) vx[e] = f2bf(xrow[off + e]);   // scalar (stride 129)
            ax[ks] = vx;
            float4v ha = *(const float4v*)(hrow + off);
            float4v hb4 = *(const float4v*)(hrow + off + 4);
            float4v na = *(const float4v*)(nrow + off);
            float4v nb4 = *(const float4v*)(nrow + off + 4);
            bf16x8 vh, vn;
            #pragma unroll
            for (int e = 0; e < 4; ++e) {
                vh[e] = f2bf(ha[e]);  vh[e + 4] = f2bf(hb4[e]);
                vn[e] = f2bf(na[e]);  vn[e + 4] = f2bf(nb4[e]);
            }
            ah[ks] = vh;
            an[ks] = vn;
        }
    }

    // ---- GEMM1 (swapped): acc[j] = pre^T[k = w*32+j*16+l4*4+q][row = l15] ----
    f32x4 acc_h[2], acc_n[2];
    {
        f32x4 accx[2];
        #pragma unroll
        for (int j = 0; j < 2; ++j) accx[j] = base[j];
        #pragma unroll
        for (int ks = 0; ks < 4; ++ks)
            #pragma unroll
            for (int j = 0; j < 2; ++j)
                accx[j] = __builtin_amdgcn_mfma_f32_16x16x32_bf16(bx[j][ks], ax[ks], accx[j], 0, 0, 0);
        #pragma unroll
        for (int j = 0; j < 2; ++j) { acc_h[j] = accx[j]; acc_n[j] = accx[j]; }
        #pragma unroll
        for (int ks = 0; ks < 4; ++ks)
            #pragma unroll
            for (int j = 0; j < 2; ++j) {
                acc_h[j] = __builtin_amdgcn_mfma_f32_16x16x32_bf16(bh[j][ks], ah[ks], acc_h[j], 0, 0, 0);
                acc_n[j] = __builtin_amdgcn_mfma_f32_16x16x32_bf16(bh[j][ks], an[ks], acc_n[j], 0, 0, 0);
            }
    }

    // ---- prefetch first half of GEMM2 W2 frags (waves 0..7): hides under epilogue A ----
    bf16x8 b2f[8];
    if (w < 8) {
        #pragma unroll
        for (int ks = 0; ks < 8; ++ks)
            b2f[ks] = *(const bf16x8*)&w2p[((w * 16 + ks) * 64 + lane) * 8];
    }

    // ---- epilogue A: tanh -> ab (b64 writes); div partial = local sum + 2 shfl ----
    float dph = 0.f, dpn = 0.f;
    #pragma unroll
    for (int j = 0; j < 2; ++j) {
        int k0 = w * 32 + j * 16 + l4 * 4;
        float4v c4 = *(const float4v*)&c[k0];
        bf16x4 ph, pn;
        #pragma unroll
        for (int q = 0; q < 4; ++q) {
            float a1 = fast_tanh(acc_h[j][q]);
            float a2 = fast_tanh(acc_n[j][q]);
            ph[q] = f2bf(a1);
            pn[q] = f2bf(a2);
            dph += (1.f - a1 * a1) * c4[q];
            dpn += (1.f - a2 * a2) * c4[q];
        }
        *(bf16x4*)&ab_h[l15][k0] = ph;
        *(bf16x4*)&ab_n[l15][k0] = pn;
    }
    dph += __shfl_xor(dph, 16, 64);  dph += __shfl_xor(dph, 32, 64);
    dpn += __shfl_xor(dpn, 16, 64);  dpn += __shfl_xor(dpn, 32, 64);
    if (l4 == 0) {
        divp[0][w][l15] = dph;
        divp[1][w][l15] = dpn;
    }
    __syncthreads();

    // ---- GEMM2: waves 0..7, full K=512, out cols [w*16, w*16+16) ----
    if (w < 8) {
        f32x4 avh = (f32x4){0, 0, 0, 0}, avn = (f32x4){0, 0, 0, 0};
        #pragma unroll
        for (int ks = 0; ks < 8; ++ks) {
            bf16x8 afh = *(const bf16x8*)&ab_h[l15][ks * 32 + l4 * 8];
            bf16x8 afn = *(const bf16x8*)&ab_n[l15][ks * 32 + l4 * 8];
            avh = __builtin_amdgcn_mfma_f32_16x16x32_bf16(afh, b2f[ks], avh, 0, 0, 0);
            avn = __builtin_amdgcn_mfma_f32_16x16x32_bf16(afn, b2f[ks], avn, 0, 0, 0);
        }
        bf16x8 b2g[8];
        #pragma unroll
        for (int ks = 0; ks < 8; ++ks)
            b2g[ks] = *(const bf16x8*)&w2p[((w * 16 + 8 + ks) * 64 + lane) * 8];
        #pragma unroll
        for (int ks = 0; ks < 8; ++ks) {
            bf16x8 afh = *(const bf16x8*)&ab_h[l15][(8 + ks) * 32 + l4 * 8];
            bf16x8 afn = *(const bf16x8*)&ab_n[l15][(8 + ks) * 32 + l4 * 8];
            avh = __builtin_amdgcn_mfma_f32_16x16x32_bf16(afh, b2g[ks], avh, 0, 0, 0);
            avn = __builtin_amdgcn_mfma_f32_16x16x32_bf16(afn, b2g[ks], avn, 0, 0, 0);
        }
        int col = w * 16 + l15;
        float bb = b2[col];
        #pragma unroll
        for (int q = 0; q < 4; ++q) {
            int r = l4 * 4 + q;
            float v = (1.f - gs) * avn[q] + gs * avh[q] + bb;
            out[(row0 + r) * OUTC + col] = v;
        }
    } else if (w == 8 && lane < ROWS) {
        float dh = 0.f, dn = 0.f;
        #pragma unroll
        for (int ww = 0; ww < 16; ++ww) { dh += divp[0][ww][lane]; dn += divp[1][ww][lane]; }
        out[(row0 + lane) * OUTC + DX] = (1.f - gs) * dn + gs * dh;
    }
}

extern "C" void kernel_launch(void* const* d_in, const int* in_sizes, int n_in,
                              void* d_out, int out_size, void* d_ws, size_t ws_size,
                              hipStream_t stream) {
    const float* state = (const float*)d_in[0];
    const float* h     = (const float*)d_in[1];
    const float* hn    = (const float*)d_in[2];
    const float* t     = (const float*)d_in[3];
    const float* gs    = (const float*)d_in[4];
    const float* W1    = (const float*)d_in[5];
    const float* b1    = (const float*)d_in[6];
    const float* W2    = (const float*)d_in[7];
    const float* b2    = (const float*)d_in[8];
    float* out = (float*)d_out;

    // workspace layout: c (512 f32) | W1P (131072 bf16) | W2P (65536 bf16)  ~= 390 KB
    float* c   = (float*)d_ws;
    short* w1p = (short*)((char*)d_ws + 2048);
    short* w2p = (short*)((char*)d_ws + 2048 + 262144);

    prep_kernel<<<224, 256, 0, stream>>>(W1, W2, c, w1p, w2p);
    cvf_kernel<<<NB / ROWS, 1024, 0, stream>>>(state, h, hn, t, gs, W1, b1, b2, c, w1p, w2p, out);
}

// Round 11
// 20.648 us; speedup vs baseline: 1.3234x; 1.3234x over previous
//
#include <hip/hip_runtime.h>
#include <hip/hip_bf16.h>

#define DX 128
#define DH 128
#define HID 512
#define NB 4096
#define ROWS 16
#define OUTC 129   // 128 v cols + 1 div col

typedef __attribute__((ext_vector_type(4))) float f32x4;
typedef __attribute__((ext_vector_type(4))) float float4v;
typedef __attribute__((ext_vector_type(2))) float float2v;
typedef __attribute__((ext_vector_type(8))) short bf16x8;
typedef __attribute__((ext_vector_type(4))) short bf16x4;
typedef __attribute__((ext_vector_type(2))) short bf16x2;

// RNE float -> bf16 (bit pattern in a short)
__device__ inline short f2bf(float f) {
    unsigned u = __float_as_uint(f);
    unsigned r = (u + 0x7fffu + ((u >> 16) & 1u)) >> 16;
    return (short)r;
}

__device__ inline float fast_tanh(float x) {
    float e = __expf(2.0f * x);
    float r = __builtin_amdgcn_rcpf(e + 1.0f);
    return 1.0f - 2.0f * r;
}

// ---- SINGLE-dispatch kernel: per-block weight self-service, spill-disciplined ----
// (R8 retry with the spill fixed: fragments are STREAMED per-ks, never batched 32-wide.)
// GEMM1 (swapped, R7-verified): wave w owns hidden cols [w*32,w*32+32); acc = pre^T.
//   W1 frags: direct global fp32, per-e coalesced (16 consecutive l15 floats/instr).
// c via MFMA (R8-verified): Dc[j] = sum_ks mfma(bx[j][ks], w2f[j][ks]); w2f built by
//   per-wave LDS tile transpose (padded +8 shorts -> ~2-way banks); diag via shfl.
// GEMM2 (R7-verified): waves 0..7 full-K, out cols [w*16,w*16+16); W2 frags direct
//   from global, per-e coalesced. Wave 8 finalizes div. Single __syncthreads pair.
__global__ __launch_bounds__(1024) void cvf_kernel(
    const float* __restrict__ state, const float* __restrict__ h_,
    const float* __restrict__ hn_, const float* __restrict__ tptr,
    const float* __restrict__ gsptr, const float* __restrict__ W1,
    const float* __restrict__ b1, const float* __restrict__ b2,
    const float* __restrict__ W2, float* __restrict__ out)
{
    __shared__ short xb [ROWS][DX + 8];
    __shared__ short hb [ROWS][DH + 8];
    __shared__ short hnb[ROWS][DH + 8];
    __shared__ short ab_h[ROWS][HID + 8];
    __shared__ short ab_n[ROWS][HID + 8];
    __shared__ short tb [16][16][40];        // per-wave 16x32(+8 pad) transpose tile
    __shared__ float divp[2][16][ROWS];

    const int tid  = threadIdx.x;
    const int lane = tid & 63;
    const int w    = tid >> 6;         // wave 0..15
    const int l15  = lane & 15;
    const int l4   = lane >> 4;
    const int row0 = blockIdx.x * ROWS;
    const float t  = tptr[0];
    const float gs = gsptr[0];

    // ---- stage x / h / h_null as bf16 into LDS (1024 threads: 2 floats each) ----
    {
        int r  = tid >> 6;            // 0..15
        int c0 = (tid & 63) * 2;      // 0..126
        const float* sp = state + (row0 + r) * OUTC + c0;   // x = state[:, :128]
        float2v vh = *(const float2v*)(h_  + (row0 + r) * DH + c0);
        float2v vn = *(const float2v*)(hn_ + (row0 + r) * DH + c0);
        bf16x2 sx, sh, sn;
        #pragma unroll
        for (int e = 0; e < 2; ++e) {
            sx[e] = f2bf(sp[e]);
            sh[e] = f2bf(vh[e]);
            sn[e] = f2bf(vn[e]);
        }
        *(bf16x2*)&xb [r][c0] = sx;
        *(bf16x2*)&hb [r][c0] = sh;
        *(bf16x2*)&hnb[r][c0] = sn;
    }

    // ---- build w2f[2][4] (W2^T frags for c-MFMA) via per-wave padded LDS transpose ----
    // (wave-private tile: same-wave ds_write->ds_read, compiler inserts lgkmcnt; no barrier)
    bf16x8 w2f[2][4];
    #pragma unroll
    for (int g = 0; g < 2; ++g) {
        int kt = 2 * w + g;
        #pragma unroll
        for (int q2 = 0; q2 < 4; ++q2) {
            int rr = lane >> 3;            // 0..7
            int cc = (lane & 7) * 4;       // 0..28
            float4v t0 = *(const float4v*)&W2[(kt * 16 + rr)     * DX + q2 * 32 + cc];
            float4v t1 = *(const float4v*)&W2[(kt * 16 + 8 + rr) * DX + q2 * 32 + cc];
            bf16x4 b0, b1v;
            #pragma unroll
            for (int e = 0; e < 4; ++e) { b0[e] = f2bf(t0[e]); b1v[e] = f2bf(t1[e]); }
            *(bf16x4*)&tb[w][rr][cc]     = b0;
            *(bf16x4*)&tb[w][rr + 8][cc] = b1v;
            w2f[g][q2] = *(const bf16x8*)&tb[w][l15][l4 * 8];   // transposed read
        }
    }

    // ---- base fold (b1 + t*W1[256,:]) ----
    f32x4 base[2];
    #pragma unroll
    for (int j = 0; j < 2; ++j) {
        int k0 = w * 32 + j * 16 + l4 * 4;
        float4v bb = *(const float4v*)&b1[k0];
        float4v tw = *(const float4v*)&W1[256 * HID + k0];
        #pragma unroll
        for (int q = 0; q < 4; ++q) base[j][q] = bb[q] + t * tw[q];
    }
    __syncthreads();

    // ---- GEMM1 (swapped) + c-MFMA, W1 frags STREAMED per (ks, j) ----
    f32x4 acc_h[2], acc_n[2], Dc[2];
    {
        f32x4 accx[2];
        #pragma unroll
        for (int j = 0; j < 2; ++j) { accx[j] = base[j]; Dc[j] = (f32x4){0, 0, 0, 0}; }

        #pragma unroll
        for (int ks = 0; ks < 4; ++ks) {              // x part: K = 128
            bf16x8 ax = *(const bf16x8*)&xb[l15][ks * 32 + l4 * 8];
            #pragma unroll
            for (int j = 0; j < 2; ++j) {
                const float* p = W1 + (ks * 32 + l4 * 8) * HID + w * 32 + j * 16 + l15;
                bf16x8 bxf;
                #pragma unroll
                for (int e = 0; e < 8; ++e) bxf[e] = f2bf(p[e * HID]);
                accx[j] = __builtin_amdgcn_mfma_f32_16x16x32_bf16(bxf, ax, accx[j], 0, 0, 0);
                Dc[j]   = __builtin_amdgcn_mfma_f32_16x16x32_bf16(bxf, w2f[j][ks], Dc[j], 0, 0, 0);
            }
        }
        #pragma unroll
        for (int j = 0; j < 2; ++j) { acc_h[j] = accx[j]; acc_n[j] = accx[j]; }

        #pragma unroll
        for (int ks = 0; ks < 4; ++ks) {              // h / h_null part: K = 128
            bf16x8 ah = *(const bf16x8*)&hb [l15][ks * 32 + l4 * 8];
            bf16x8 an = *(const bf16x8*)&hnb[l15][ks * 32 + l4 * 8];
            #pragma unroll
            for (int j = 0; j < 2; ++j) {
                const float* p = W1 + (128 + ks * 32 + l4 * 8) * HID + w * 32 + j * 16 + l15;
                bf16x8 bhf;
                #pragma unroll
                for (int e = 0; e < 8; ++e) bhf[e] = f2bf(p[e * HID]);
                acc_h[j] = __builtin_amdgcn_mfma_f32_16x16x32_bf16(bhf, ah, acc_h[j], 0, 0, 0);
                acc_n[j] = __builtin_amdgcn_mfma_f32_16x16x32_bf16(bhf, an, acc_n[j], 0, 0, 0);
            }
        }
    }

    // ---- prefetch first half of GEMM2 W2 frags (waves 0..7), per-e coalesced ----
    bf16x8 b2f[8];
    if (w < 8) {
        #pragma unroll
        for (int ks = 0; ks < 8; ++ks) {
            const float* p = W2 + (ks * 32 + l4 * 8) * DX + w * 16 + l15;
            bf16x8 v;
            #pragma unroll
            for (int e = 0; e < 8; ++e) v[e] = f2bf(p[e * DX]);
            b2f[ks] = v;
        }
    }

    // ---- epilogue A: tanh -> ab (b64 writes); div partial with c4 from Dc diag ----
    float dph = 0.f, dpn = 0.f;
    #pragma unroll
    for (int j = 0; j < 2; ++j) {
        int k0 = w * 32 + j * 16 + l4 * 4;
        f32x4 c4;
        #pragma unroll
        for (int q = 0; q < 4; ++q)
            c4[q] = __shfl(Dc[j][q], 20 * l4 + q, 64);   // diag holder lane (R8-verified)
        bf16x4 ph, pn;
        #pragma unroll
        for (int q = 0; q < 4; ++q) {
            float a1 = fast_tanh(acc_h[j][q]);
            float a2 = fast_tanh(acc_n[j][q]);
            ph[q] = f2bf(a1);
            pn[q] = f2bf(a2);
            dph += (1.f - a1 * a1) * c4[q];
            dpn += (1.f - a2 * a2) * c4[q];
        }
        *(bf16x4*)&ab_h[l15][k0] = ph;
        *(bf16x4*)&ab_n[l15][k0] = pn;
    }
    dph += __shfl_xor(dph, 16, 64);  dph += __shfl_xor(dph, 32, 64);
    dpn += __shfl_xor(dpn, 16, 64);  dpn += __shfl_xor(dpn, 32, 64);
    if (l4 == 0) {
        divp[0][w][l15] = dph;
        divp[1][w][l15] = dpn;
    }
    __syncthreads();

    // ---- GEMM2: waves 0..7, full K=512, out cols [w*16, w*16+16) ----
    if (w < 8) {
        f32x4 avh = (f32x4){0, 0, 0, 0}, avn = (f32x4){0, 0, 0, 0};
        #pragma unroll
        for (int ks = 0; ks < 8; ++ks) {
            bf16x8 afh = *(const bf16x8*)&ab_h[l15][ks * 32 + l4 * 8];
            bf16x8 afn = *(const bf16x8*)&ab_n[l15][ks * 32 + l4 * 8];
            avh = __builtin_amdgcn_mfma_f32_16x16x32_bf16(afh, b2f[ks], avh, 0, 0, 0);
            avn = __builtin_amdgcn_mfma_f32_16x16x32_bf16(afn, b2f[ks], avn, 0, 0, 0);
        }
        #pragma unroll
        for (int ks = 0; ks < 8; ++ks) {               // second half: streamed
            const float* p = W2 + ((8 + ks) * 32 + l4 * 8) * DX + w * 16 + l15;
            bf16x8 bg;
            #pragma unroll
            for (int e = 0; e < 8; ++e) bg[e] = f2bf(p[e * DX]);
            bf16x8 afh = *(const bf16x8*)&ab_h[l15][(8 + ks) * 32 + l4 * 8];
            bf16x8 afn = *(const bf16x8*)&ab_n[l15][(8 + ks) * 32 + l4 * 8];
            avh = __builtin_amdgcn_mfma_f32_16x16x32_bf16(afh, bg, avh, 0, 0, 0);
            avn = __builtin_amdgcn_mfma_f32_16x16x32_bf16(afn, bg, avn, 0, 0, 0);
        }
        int col = w * 16 + l15;
        float bb = b2[col];
        #pragma unroll
        for (int q = 0; q < 4; ++q) {
            int r = l4 * 4 + q;
            float v = (1.f - gs) * avn[q] + gs * avh[q] + bb;
            out[(row0 + r) * OUTC + col] = v;
        }
    } else if (w == 8 && lane < ROWS) {
        float dh = 0.f, dn = 0.f;
        #pragma unroll
        for (int ww = 0; ww < 16; ++ww) { dh += divp[0][ww][lane]; dn += divp[1][ww][lane]; }
        out[(row0 + lane) * OUTC + DX] = (1.f - gs) * dn + gs * dh;
    }
}

extern "C" void kernel_launch(void* const* d_in, const int* in_sizes, int n_in,
                              void* d_out, int out_size, void* d_ws, size_t ws_size,
                              hipStream_t stream) {
    const float* state = (const float*)d_in[0];
    const float* h     = (const float*)d_in[1];
    const float* hn    = (const float*)d_in[2];
    const float* t     = (const float*)d_in[3];
    const float* gs    = (const float*)d_in[4];
    const float* W1    = (const float*)d_in[5];
    const float* b1    = (const float*)d_in[6];
    const float* W2    = (const float*)d_in[7];
    const float* b2    = (const float*)d_in[8];
    float* out = (float*)d_out;

    cvf_kernel<<<NB / ROWS, 1024, 0, stream>>>(state, h, hn, t, gs, W1, b1, b2, W2, out);
}

// Round 12
// 17.568 us; speedup vs baseline: 1.5554x; 1.1753x over previous
//
#include <hip/hip_runtime.h>
#include <hip/hip_bf16.h>

#define DX 128
#define DH 128
#define HID 512
#define NB 4096
#define ROWS 16
#define OUTC 129   // 128 v cols + 1 div col

typedef __attribute__((ext_vector_type(4))) float f32x4;
typedef __attribute__((ext_vector_type(4))) float float4v;
typedef __attribute__((ext_vector_type(2))) float float2v;
typedef __attribute__((ext_vector_type(8))) short bf16x8;
typedef __attribute__((ext_vector_type(4))) short bf16x4;
typedef __attribute__((ext_vector_type(2))) short bf16x2;

// RNE float -> bf16 (bit pattern in a short)
__device__ inline short f2bf(float f) {
    unsigned u = __float_as_uint(f);
    unsigned r = (u + 0x7fffu + ((u >> 16) & 1u)) >> 16;
    return (short)r;
}

__device__ inline float fast_tanh(float x) {
    float e = __expf(2.0f * x);
    float r = __builtin_amdgcn_rcpf(e + 1.0f);
    return 1.0f - 2.0f * r;
}

// -------- prep v2 (unchanged, proven): wave-per-tile coalesced repack --------
// W1P layout: [nt(32)][ks(8)][lane(64)][e(8)] -> W1[(ks*32+(l>>4)*8+e), nt*16+(l&15)]
// W2P layout: [nt(8)][ks(16)][lane(64)][e(8)] -> W2[(ks*32+(l>>4)*8+e), nt*16+(l&15)]
__global__ __launch_bounds__(256) void prep_kernel(
    const float* __restrict__ W1, const float* __restrict__ W2,
    float* __restrict__ c, short* __restrict__ w1p, short* __restrict__ w2p)
{
    __shared__ float tile[4][32][17];

    const int tid  = threadIdx.x;
    const int lane = tid & 63;
    const int w    = tid >> 6;
    const int l15  = lane & 15;
    const int l4   = lane >> 4;
    const int W    = blockIdx.x * 4 + w;

    if (W < 256) {                         // w1p tile
        int nt = W >> 3, ks = W & 7;
        int m0 = ks * 32, n0 = nt * 16;
        #pragma unroll
        for (int p = 0; p < 8; ++p) {
            int r = p * 4 + l4;
            tile[w][r][l15] = W1[(m0 + r) * HID + n0 + l15];
        }
    } else if (W < 384) {                  // w2p tile
        int idx = W - 256;
        int nt = idx >> 4, ks = idx & 15;
        int k0 = ks * 32, n0 = nt * 16;
        #pragma unroll
        for (int p = 0; p < 8; ++p) {
            int r = p * 4 + l4;
            tile[w][r][l15] = W2[(k0 + r) * DX + n0 + l15];
        }
    }
    __syncthreads();

    if (W < 256) {
        bf16x8 v;
        #pragma unroll
        for (int e = 0; e < 8; ++e) v[e] = f2bf(tile[w][l4 * 8 + e][l15]);
        *(bf16x8*)&w1p[W * 512 + lane * 8] = v;
    } else if (W < 384) {
        int idx = W - 256;
        bf16x8 v;
        #pragma unroll
        for (int e = 0; e < 8; ++e) v[e] = f2bf(tile[w][l4 * 8 + e][l15]);
        *(bf16x8*)&w2p[idx * 512 + lane * 8] = v;
    } else if (W < 896) {                  // c[k] = sum_i W1[i,k]*W2[k,i]
        int k = W - 384;
        float p = W1[lane * HID + k] * W2[k * DX + lane]
                + W1[(lane + 64) * HID + k] * W2[k * DX + lane + 64];
        for (int m = 1; m < 64; m <<= 1) p += __shfl_xor(p, m, 64);
        if (lane == 0) c[k] = p;
    }
}

// -------- cvf v6: blend-before-GEMM2 (GEMM2 is linear in a) --------
// GEMM1 (swapped): wave w owns hidden cols [w*32,w*32+32); acc = pre^T; lane holds
//   pre^T[k = w*32+j*16+l4*4+q][row = l15] (k-consecutive per lane).
// epilogue A: a_blend = gs*tanh(pre_h) + (1-gs)*tanh(pre_n) -> ONE ab (b64 writes);
//   div partial blended per-thread -> ONE divp.
// GEMM2 (K-split, single accumulator): wave pair (2m,2m+1) -> out cols [m*16,m*16+16);
//   even wave K=0..255, odd K=256..511; red exchange halved (one branch).
__global__ __launch_bounds__(1024) void cvf_kernel(
    const float* __restrict__ state, const float* __restrict__ h_,
    const float* __restrict__ hn_, const float* __restrict__ tptr,
    const float* __restrict__ gsptr, const float* __restrict__ W1,
    const float* __restrict__ b1, const float* __restrict__ b2,
    const float* __restrict__ c, const short* __restrict__ w1p,
    const short* __restrict__ w2p, float* __restrict__ out)
{
    __shared__ short xb [ROWS][DX + 8];
    __shared__ short hb [ROWS][DH + 8];
    __shared__ short hnb[ROWS][DH + 8];
    __shared__ short ab [ROWS][HID + 8];     // blended activations (16 KB, was 32)
    __shared__ float divp[16][ROWS];         // blended div partials
    __shared__ float red[8][64][4];          // K-split partial exchange (8 KB, was 16)

    const int tid  = threadIdx.x;
    const int lane = tid & 63;
    const int w    = tid >> 6;         // wave 0..15
    const int l15  = lane & 15;
    const int l4   = lane >> 4;
    const int row0 = blockIdx.x * ROWS;
    const float t  = tptr[0];
    const float gs = gsptr[0];
    const float gn = 1.0f - gs;

    // ---- prefetch: all 8 x-part W1 frags + vectorized base fold ----
    bf16x8 bx[2][4];
    f32x4 base[2];
    #pragma unroll
    for (int j = 0; j < 2; ++j) {
        #pragma unroll
        for (int ks = 0; ks < 4; ++ks)
            bx[j][ks] = *(const bf16x8*)&w1p[(((w * 2 + j) * 8 + ks) * 64 + lane) * 8];
        int k0 = w * 32 + j * 16 + l4 * 4;
        float4v bb = *(const float4v*)&b1[k0];
        float4v tw = *(const float4v*)&W1[256 * HID + k0];
        #pragma unroll
        for (int q = 0; q < 4; ++q) base[j][q] = bb[q] + t * tw[q];
    }

    // ---- stage x / h / h_null as bf16 into LDS (1024 threads: 2 floats each) ----
    {
        int r  = tid >> 6;            // 0..15
        int c0 = (tid & 63) * 2;      // 0..126
        const float* sp = state + (row0 + r) * OUTC + c0;   // x = state[:, :128]
        float2v vh = *(const float2v*)(h_  + (row0 + r) * DH + c0);
        float2v vn = *(const float2v*)(hn_ + (row0 + r) * DH + c0);
        bf16x2 sx, sh, sn;
        #pragma unroll
        for (int e = 0; e < 2; ++e) {
            sx[e] = f2bf(sp[e]);
            sh[e] = f2bf(vh[e]);
            sn[e] = f2bf(vn[e]);
        }
        *(bf16x2*)&xb [r][c0] = sx;
        *(bf16x2*)&hb [r][c0] = sh;
        *(bf16x2*)&hnb[r][c0] = sn;
    }
    __syncthreads();

    // ---- GEMM1 (swapped): acc[j] = pre^T[k = w*32+j*16+l4*4+q][row = l15] ----
    f32x4 acc_h[2], acc_n[2];
    {
        bf16x8 ax[4];
        #pragma unroll
        for (int ks = 0; ks < 4; ++ks)
            ax[ks] = *(const bf16x8*)&xb[l15][ks * 32 + l4 * 8];

        f32x4 accx[2];
        #pragma unroll
        for (int j = 0; j < 2; ++j) accx[j] = base[j];
        #pragma unroll
        for (int ks = 0; ks < 4; ++ks)
            #pragma unroll
            for (int j = 0; j < 2; ++j)
                accx[j] = __builtin_amdgcn_mfma_f32_16x16x32_bf16(bx[j][ks], ax[ks], accx[j], 0, 0, 0);

        bf16x8 bh[2][4];
        #pragma unroll
        for (int j = 0; j < 2; ++j)
            #pragma unroll
            for (int ks = 0; ks < 4; ++ks)
                bh[j][ks] = *(const bf16x8*)&w1p[(((w * 2 + j) * 8 + 4 + ks) * 64 + lane) * 8];
        bf16x8 ah[4], an[4];
        #pragma unroll
        for (int ks = 0; ks < 4; ++ks) {
            ah[ks] = *(const bf16x8*)&hb [l15][ks * 32 + l4 * 8];
            an[ks] = *(const bf16x8*)&hnb[l15][ks * 32 + l4 * 8];
        }

        #pragma unroll
        for (int j = 0; j < 2; ++j) { acc_h[j] = accx[j]; acc_n[j] = accx[j]; }
        #pragma unroll
        for (int ks = 0; ks < 4; ++ks)
            #pragma unroll
            for (int j = 0; j < 2; ++j) {
                acc_h[j] = __builtin_amdgcn_mfma_f32_16x16x32_bf16(bh[j][ks], ah[ks], acc_h[j], 0, 0, 0);
                acc_n[j] = __builtin_amdgcn_mfma_f32_16x16x32_bf16(bh[j][ks], an[ks], acc_n[j], 0, 0, 0);
            }
    }

    // ---- prefetch this wave's GEMM2 W2 frags (K-split half): hides under epilogue A ----
    const int nt2 = w >> 1;
    const int ks0 = (w & 1) * 8;
    bf16x8 b2f[8];
    #pragma unroll
    for (int ks = 0; ks < 8; ++ks)
        b2f[ks] = *(const bf16x8*)&w2p[((nt2 * 16 + ks0 + ks) * 64 + lane) * 8];

    // ---- epilogue A: blended a -> ab (b64); blended div partial ----
    float dp = 0.f;
    #pragma unroll
    for (int j = 0; j < 2; ++j) {
        int k0 = w * 32 + j * 16 + l4 * 4;
        float4v c4 = *(const float4v*)&c[k0];
        bf16x4 pb;
        #pragma unroll
        for (int q = 0; q < 4; ++q) {
            float a1 = fast_tanh(acc_h[j][q]);
            float a2 = fast_tanh(acc_n[j][q]);
            pb[q] = f2bf(gs * a1 + gn * a2);
            dp += (gs * (1.f - a1 * a1) + gn * (1.f - a2 * a2)) * c4[q];
        }
        *(bf16x4*)&ab[l15][k0] = pb;
    }
    dp += __shfl_xor(dp, 16, 64);
    dp += __shfl_xor(dp, 32, 64);
    if (l4 == 0) divp[w][l15] = dp;
    __syncthreads();

    // ---- GEMM2 (K-split, single acc): wave pair (2m,2m+1) -> cols [m*16,m*16+16) ----
    f32x4 av = (f32x4){0, 0, 0, 0};
    #pragma unroll
    for (int ks = 0; ks < 8; ++ks) {
        bf16x8 af = *(const bf16x8*)&ab[l15][(ks0 + ks) * 32 + l4 * 8];
        av = __builtin_amdgcn_mfma_f32_16x16x32_bf16(af, b2f[ks], av, 0, 0, 0);
    }
    if (w & 1) {
        #pragma unroll
        for (int q = 0; q < 4; ++q) red[nt2][lane][q] = av[q];
    }
    __syncthreads();

    // ---- epilogue B: even waves combine partials + bias, write v ----
    if (!(w & 1)) {
        int col = nt2 * 16 + l15;
        float bb = b2[col];
        #pragma unroll
        for (int q = 0; q < 4; ++q) {
            int r = l4 * 4 + q;
            out[(row0 + r) * OUTC + col] = av[q] + red[nt2][lane][q] + bb;
        }
    } else if (w == 1 && lane < ROWS) {
        // ---- div: sum 16 blended wave partials, write col 128 ----
        float d = 0.f;
        #pragma unroll
        for (int ww = 0; ww < 16; ++ww) d += divp[ww][lane];
        out[(row0 + lane) * OUTC + DX] = d;
    }
}

extern "C" void kernel_launch(void* const* d_in, const int* in_sizes, int n_in,
                              void* d_out, int out_size, void* d_ws, size_t ws_size,
                              hipStream_t stream) {
    const float* state = (const float*)d_in[0];
    const float* h     = (const float*)d_in[1];
    const float* hn    = (const float*)d_in[2];
    const float* t     = (const float*)d_in[3];
    const float* gs    = (const float*)d_in[4];
    const float* W1    = (const float*)d_in[5];
    const float* b1    = (const float*)d_in[6];
    const float* W2    = (const float*)d_in[7];
    const float* b2    = (const float*)d_in[8];
    float* out = (float*)d_out;

    // workspace layout: c (512 f32) | W1P (131072 bf16) | W2P (65536 bf16)  ~= 390 KB
    float* c   = (float*)d_ws;
    short* w1p = (short*)((char*)d_ws + 2048);
    short* w2p = (short*)((char*)d_ws + 2048 + 262144);

    prep_kernel<<<224, 256, 0, stream>>>(W1, W2, c, w1p, w2p);
    cvf_kernel<<<NB / ROWS, 1024, 0, stream>>>(state, h, hn, t, gs, W1, b1, b2, c, w1p, w2p, out);
}